// Round 10
// baseline (118.752 us; speedup 1.0000x reference)
//
#include <hip/hip_runtime.h>
#include <hip/hip_fp16.h>

#define N_NODES 100000
#define N_EDGES 1600000

#define NPB   256                      // nodes per bucket
#define NB    391                      // ceil(100000/256)
#define PCAP  8192                     // pairs capacity per bucket
#define SCAP  32                       // LDS staging slots per bucket
#define ABLK  64                       // phase-A blocks (fewer -> fewer final-flush atomics)
#define ATHR  1024                     // phase-A threads
#define BATCH 4096                     // edges per block-iteration (4/thread)
#define CAP   64                       // per-node CSR row capacity

typedef unsigned int u32;

__device__ __forceinline__ float2 h2f2(u32 u) {
    __half2 h = *reinterpret_cast<__half2*>(&u);
    return __half22float2(h);
}

// zero the tail counters on the compute queue
__global__ void zero_tail_kernel(int* __restrict__ tail) {
    tail[threadIdx.x] = 0;
}

// ---------------- Phase A: bucket edges with line-granular flushes ----------------
// pair = (src<<8) | (dst & 255); bucket = dst >> 8; sentinel = -1
// Flush only when >=24 pairs staged: ~3x fewer contended tail atomics than per-batch flushing.
__global__ __launch_bounds__(ATHR) void bucket_kernel(
    const int* __restrict__ src, const int* __restrict__ dst,
    int* __restrict__ tail, int* __restrict__ pairs, int E) {
    __shared__ int lcnt[NB];
    __shared__ int stage[NB * SCAP];
    const int tid = threadIdx.x;
    for (int b = tid; b < NB; b += ATHR) lcnt[b] = 0;
    __syncthreads();

    const int chunk = (E + gridDim.x - 1) / gridDim.x;
    const int e0 = blockIdx.x * chunk;
    const int e1 = min(e0 + chunk, E);

    for (int be = e0; be < e1; be += BATCH) {
#pragma unroll
        for (int q = 0; q < 4; ++q) {
            int e = be + q * ATHR + tid;
            if (e < e1) {
                int d = dst[e];
                int p = (src[e] << 8) | (d & 255);
                int b = d >> 8;
                int pos = atomicAdd(&lcnt[b], 1);
                if (pos < SCAP) {
                    stage[b * SCAP + pos] = p;
                } else {
                    // overflow fallback (rare): grab a full aligned group, pad with sentinels
                    int g = atomicAdd(&tail[b], 8);
                    if (g + 8 <= PCAP) {
                        pairs[b * PCAP + g] = p;
                        for (int j = 1; j < 8; ++j) pairs[b * PCAP + g + j] = -1;
                    }
                }
            }
        }
        __syncthreads();
        // amortized flush: only when >=24 staged; flush all full groups of 8
        for (int b = tid; b < NB; b += ATHR) {
            int n = min(lcnt[b], SCAP);
            if (n >= 24) {
                int ng = n >> 3;
                int base = atomicAdd(&tail[b], ng * 8);
                int4* gdst = (int4*)(pairs + b * PCAP + base);
                int4* lsrc = (int4*)(stage + b * SCAP);
                for (int g = 0; g < ng; ++g) {
                    if (base + g * 8 + 8 <= PCAP) {
                        gdst[g * 2]     = lsrc[g * 2];
                        gdst[g * 2 + 1] = lsrc[g * 2 + 1];
                    }
                }
                int rem = n & 7;
                for (int j = 0; j < rem; ++j) stage[b * SCAP + j] = stage[b * SCAP + ng * 8 + j];
                lcnt[b] = rem;
            } else {
                lcnt[b] = n;   // clamp if overflowed
            }
        }
        __syncthreads();
    }
    // final flush: pad remainder to a full group with sentinels
    for (int b = tid; b < NB; b += ATHR) {
        int n = min(lcnt[b], SCAP);
        if (n) {
            int ng = (n + 7) >> 3;
            for (int j = n; j < ng * 8; ++j) stage[b * SCAP + j] = -1;
            int base = atomicAdd(&tail[b], ng * 8);
            int4* gdst = (int4*)(pairs + b * PCAP + base);
            int4* lsrc = (int4*)(stage + b * SCAP);
            for (int g = 0; g < ng; ++g) {
                if (base + g * 8 + 8 <= PCAP) {
                    gdst[g * 2]     = lsrc[g * 2];
                    gdst[g * 2 + 1] = lsrc[g * 2 + 1];
                }
            }
        }
    }
}

// ---------------- Phase B: pairs -> CSR rows + fused dinv + fp16 xs table ----------------
// slist rows padded to mult-of-4 with N_NODES (the zero row).
// xh[node] = 16 halves (32B): h0..h9 = x*dinv, h10..h15 = 0. Row N of xh/th zeroed.
__global__ __launch_bounds__(1024) void csr_kernel(
    const int* __restrict__ tail, const int* __restrict__ pairs,
    const float* __restrict__ x, int* __restrict__ cnt, int* __restrict__ slist,
    float* __restrict__ dinv, u32* __restrict__ xh, u32* __restrict__ th, int N) {
    __shared__ int ofs[NPB];
    const int b = blockIdx.x, tid = threadIdx.x;
    if (tid < NPB) ofs[tid] = 0;
    __syncthreads();
    const int n = min(tail[b], PCAP);
    const int* pb = pairs + b * PCAP;
    const int node0 = b * NPB;
    for (int i = tid; i < n; i += 1024) {
        int p = pb[i];
        if (p >= 0) {
            int dl = p & 255;
            int pos = atomicAdd(&ofs[dl], 1);
            if (pos < CAP) slist[(size_t)(node0 + dl) * CAP + pos] = p >> 8;
        }
    }
    __syncthreads();
    if (tid < NPB) {
        int node = node0 + tid;
        if (node < N) {
            int deg = min(ofs[tid], CAP);
            cnt[node] = deg;
            int padded = (deg + 3) & ~3;
            for (int j = deg; j < padded; ++j) slist[(size_t)node * CAP + j] = N_NODES;
            float di = rsqrtf((float)deg + 1.0f);
            dinv[node] = di;
            u32 h[8];
#pragma unroll
            for (int k = 0; k < 5; ++k) {
                __half2 hh = __floats2half2_rn(x[(size_t)node * 10 + 2 * k] * di,
                                               x[(size_t)node * 10 + 2 * k + 1] * di);
                h[k] = *reinterpret_cast<u32*>(&hh);
            }
            h[5] = h[6] = h[7] = 0u;
            u32* row = xh + (size_t)node * 8;
            ((uint4*)row)[0] = make_uint4(h[0], h[1], h[2], h[3]);
            ((uint4*)row)[1] = make_uint4(h[4], h[5], h[6], h[7]);
        }
    }
    if (b == 0 && tid == 0) {   // zero row N of both gather tables
        u32* rx = xh + (size_t)N * 8;
        u32* rt = th + (size_t)N * 8;
        ((uint4*)rx)[0] = make_uint4(0, 0, 0, 0); ((uint4*)rx)[1] = make_uint4(0, 0, 0, 0);
        ((uint4*)rt)[0] = make_uint4(0, 0, 0, 0); ((uint4*)rt)[1] = make_uint4(0, 0, 0, 0);
    }
}

// ---------------- gather-aggregate from fp16 table: 2 threads/node, uint4 each ----------------
// cg0 accumulates halves 0..7, cg1 halves 8..15 (upper 6 are zeros). fp32 accumulation.
// out12[i][0..9] = self + sum of neighbors (cols 10/11 untouched, never read).
__global__ void aggh_kernel(const u32* __restrict__ vh, const int* __restrict__ cnt,
                            const int* __restrict__ slist, float* __restrict__ out12, int N) {
    int gt = blockIdx.x * blockDim.x + threadIdx.x;
    int i = gt >> 1, cg = gt & 1;
    if (i >= N) return;
    int degi = cnt[i];
    const int* lst = slist + (size_t)i * CAP;
    float a[8];
    {
        uint4 s = *(((const uint4*)(vh + (size_t)i * 8)) + cg);
        float2 f0 = h2f2(s.x), f1 = h2f2(s.y), f2 = h2f2(s.z), f3 = h2f2(s.w);
        a[0] = f0.x; a[1] = f0.y; a[2] = f1.x; a[3] = f1.y;
        a[4] = f2.x; a[5] = f2.y; a[6] = f3.x; a[7] = f3.y;
    }
    for (int k = 0; k < degi; k += 4) {
        int4 s4 = *reinterpret_cast<const int4*>(lst + k);
        uint4 q0 = *(((const uint4*)(vh + (size_t)s4.x * 8)) + cg);
        uint4 q1 = *(((const uint4*)(vh + (size_t)s4.y * 8)) + cg);
        uint4 q2 = *(((const uint4*)(vh + (size_t)s4.z * 8)) + cg);
        uint4 q3 = *(((const uint4*)(vh + (size_t)s4.w * 8)) + cg);
        float2 f;
        f = h2f2(q0.x); a[0] += f.x; a[1] += f.y;  f = h2f2(q0.y); a[2] += f.x; a[3] += f.y;
        f = h2f2(q0.z); a[4] += f.x; a[5] += f.y;  f = h2f2(q0.w); a[6] += f.x; a[7] += f.y;
        f = h2f2(q1.x); a[0] += f.x; a[1] += f.y;  f = h2f2(q1.y); a[2] += f.x; a[3] += f.y;
        f = h2f2(q1.z); a[4] += f.x; a[5] += f.y;  f = h2f2(q1.w); a[6] += f.x; a[7] += f.y;
        f = h2f2(q2.x); a[0] += f.x; a[1] += f.y;  f = h2f2(q2.y); a[2] += f.x; a[3] += f.y;
        f = h2f2(q2.z); a[4] += f.x; a[5] += f.y;  f = h2f2(q2.w); a[6] += f.x; a[7] += f.y;
        f = h2f2(q3.x); a[0] += f.x; a[1] += f.y;  f = h2f2(q3.y); a[2] += f.x; a[3] += f.y;
        f = h2f2(q3.z); a[4] += f.x; a[5] += f.y;  f = h2f2(q3.w); a[6] += f.x; a[7] += f.y;
    }
    float* orow = out12 + (size_t)i * 12;
    if (cg == 0) {
        ((float4*)orow)[0] = make_float4(a[0], a[1], a[2], a[3]);
        ((float4*)orow)[1] = make_float4(a[4], a[5], a[6], a[7]);
    } else {
        *(float2*)(orow + 8) = make_float2(a[0], a[1]);
    }
}

// ---------------- fused MLP: ax = dinv*agg ; y = relu(ax@W1+b1) ; th = half((y@W2)*dinv) ----------------
__global__ void layer12_kernel(const float* __restrict__ agg12, const float* __restrict__ dinv,
                               const float* __restrict__ W1, const float* __restrict__ b1,
                               const float* __restrict__ W2, u32* __restrict__ th, int N) {
    __shared__ float sW1[640];
    __shared__ float sW2[640];
    __shared__ float sb1[64];
    for (int k = threadIdx.x; k < 640; k += blockDim.x) { sW1[k] = W1[k]; sW2[k] = W2[k]; }
    if (threadIdx.x < 64) sb1[threadIdx.x] = b1[threadIdx.x];
    __syncthreads();
    int i = blockIdx.x * blockDim.x + threadIdx.x;
    if (i >= N) return;
    float di = dinv[i];
    float ax[10];
#pragma unroll
    for (int k = 0; k < 10; ++k) ax[k] = di * agg12[(size_t)i * 12 + k];
    float o[10];
#pragma unroll
    for (int k = 0; k < 10; ++k) o[k] = 0.f;
    for (int c = 0; c < 64; ++c) {
        float y = sb1[c];
#pragma unroll
        for (int k = 0; k < 10; ++k) y = fmaf(ax[k], sW1[k * 64 + c], y);
        y = fmaxf(y, 0.f);
#pragma unroll
        for (int k = 0; k < 10; ++k) o[k] = fmaf(y, sW2[c * 10 + k], o[k]);
    }
    u32 h[8];
#pragma unroll
    for (int k = 0; k < 5; ++k) {
        __half2 hh = __floats2half2_rn(o[2 * k] * di, o[2 * k + 1] * di);
        h[k] = *reinterpret_cast<u32*>(&hh);
    }
    h[5] = h[6] = h[7] = 0u;
    u32* row = th + (size_t)i * 8;
    ((uint4*)row)[0] = make_uint4(h[0], h[1], h[2], h[3]);
    ((uint4*)row)[1] = make_uint4(h[4], h[5], h[6], h[7]);
}

// ---------------- final: v = dinv*agg2 + b2 ; out = log_softmax(v) ----------------
__global__ void final_kernel(const float* __restrict__ agg2_12, const float* __restrict__ dinv,
                             const float* __restrict__ b2, float* __restrict__ out, int N) {
    int i = blockIdx.x * blockDim.x + threadIdx.x;
    if (i >= N) return;
    float di = dinv[i];
    float v[10];
    float m = -1e30f;
#pragma unroll
    for (int c = 0; c < 10; ++c) {
        float u = fmaf(di, agg2_12[(size_t)i * 12 + c], b2[c]);
        v[c] = u;
        m = fmaxf(m, u);
    }
    float s = 0.f;
#pragma unroll
    for (int c = 0; c < 10; ++c) s += __expf(v[c] - m);
    float lse = __logf(s) + m;
    float2* po = (float2*)(out + (size_t)i * 10);
#pragma unroll
    for (int c = 0; c < 5; ++c) po[c] = make_float2(v[2 * c] - lse, v[2 * c + 1] - lse);
}

extern "C" void kernel_launch(void* const* d_in, const int* in_sizes, int n_in,
                              void* d_out, int out_size, void* d_ws, size_t ws_size,
                              hipStream_t stream) {
    const float* x  = (const float*)d_in[0];
    const int*   ei = (const int*)d_in[1];
    const float* W1 = (const float*)d_in[2];
    const float* b1 = (const float*)d_in[3];
    const float* W2 = (const float*)d_in[4];
    const float* b2 = (const float*)d_in[5];
    float* out = (float*)d_out;

    const int N = N_NODES, E = N_EDGES;
    const int* src = ei;
    const int* dst = ei + E;

    // ws: [tail 512i][pairs NB*PCAP][cnt N][slist N*CAP][dinv N]
    //     [xh (N+1)*8 u32][th (N+1)*8 u32][agg12 N*12 f][agg2 N*12 f]
    int*   tail  = (int*)d_ws;
    int*   pairs = tail + 512;
    int*   cnt   = pairs + (size_t)NB * PCAP;
    int*   slist = cnt + N;
    float* dinv  = (float*)(slist + (size_t)N * CAP);
    u32*   xh    = (u32*)(dinv + N);
    u32*   th    = xh + (size_t)(N + 1) * 8;
    float* agg12 = (float*)(th + (size_t)(N + 1) * 8);
    float* agg2  = agg12 + (size_t)N * 12;

    zero_tail_kernel<<<1, 512, 0, stream>>>(tail);
    bucket_kernel<<<ABLK, ATHR, 0, stream>>>(src, dst, tail, pairs, E);
    csr_kernel<<<NB, 1024, 0, stream>>>(tail, pairs, x, cnt, slist, dinv, xh, th, N);
    aggh_kernel<<<(2 * N + 255) / 256, 256, 0, stream>>>(xh, cnt, slist, agg12, N);
    layer12_kernel<<<(N + 255) / 256, 256, 0, stream>>>(agg12, dinv, W1, b1, W2, th, N);
    aggh_kernel<<<(2 * N + 255) / 256, 256, 0, stream>>>(th, cnt, slist, agg2, N);
    final_kernel<<<(N + 255) / 256, 256, 0, stream>>>(agg2, dinv, b2, out, N);
}

// Round 11
// 98.337 us; speedup vs baseline: 1.2076x; 1.2076x over previous
//
#include <hip/hip_runtime.h>
#include <hip/hip_fp16.h>

#define N_NODES 100000
#define N_EDGES 1600000

#define NPB   256                      // nodes per bucket
#define NB    391                      // ceil(100000/256)
#define PCAP  8192                     // pairs capacity per bucket
#define SCAP  32                       // LDS staging slots per bucket
#define ABLK  256                      // phase-A blocks (R7 config: latency-bound -> need blocks)
#define ATHR  1024                     // phase-A threads
#define BATCH 4096                     // edges per block-iteration (4/thread)
#define CAP   64                       // per-node CSR row capacity

typedef unsigned int u32;

__device__ __forceinline__ float2 h2f2(u32 u) {
    __half2 h = *reinterpret_cast<__half2*>(&u);
    return __half22float2(h);
}

// zero the tail counters on the compute queue
__global__ void zero_tail_kernel(int* __restrict__ tail) {
    tail[threadIdx.x] = 0;
}

// ---------------- Phase A: bucket edges with line-granular flushes ----------------
// pair = (src<<8) | (dst & 255); bucket = dst >> 8; sentinel = -1
// R7 schedule: flush ALL full groups of 8 every batch (keeps stage pressure low, no overflow).
__global__ __launch_bounds__(ATHR) void bucket_kernel(
    const int* __restrict__ src, const int* __restrict__ dst,
    int* __restrict__ tail, int* __restrict__ pairs, int E) {
    __shared__ int lcnt[NB];
    __shared__ int stage[NB * SCAP];
    const int tid = threadIdx.x;
    for (int b = tid; b < NB; b += ATHR) lcnt[b] = 0;
    __syncthreads();

    const int chunk = (E + gridDim.x - 1) / gridDim.x;
    const int e0 = blockIdx.x * chunk;
    const int e1 = min(e0 + chunk, E);

    for (int be = e0; be < e1; be += BATCH) {
#pragma unroll
        for (int q = 0; q < 4; ++q) {
            int e = be + q * ATHR + tid;
            if (e < e1) {
                int d = dst[e];
                int p = (src[e] << 8) | (d & 255);
                int b = d >> 8;
                int pos = atomicAdd(&lcnt[b], 1);
                if (pos < SCAP) {
                    stage[b * SCAP + pos] = p;
                } else {
                    // overflow fallback (rare with per-batch flushing)
                    int g = atomicAdd(&tail[b], 8);
                    if (g + 8 <= PCAP) {
                        pairs[b * PCAP + g] = p;
                        for (int j = 1; j < 8; ++j) pairs[b * PCAP + g + j] = -1;
                    }
                }
            }
        }
        __syncthreads();
        // flush full groups of 8 (32B aligned; each line chunk owned by this block)
        for (int b = tid; b < NB; b += ATHR) {
            int n = min(lcnt[b], SCAP);
            int ng = n >> 3;
            if (ng) {
                int base = atomicAdd(&tail[b], ng * 8);
                int4* gdst = (int4*)(pairs + b * PCAP + base);
                int4* lsrc = (int4*)(stage + b * SCAP);
                for (int g = 0; g < ng; ++g) {
                    if (base + g * 8 + 8 <= PCAP) {
                        gdst[g * 2]     = lsrc[g * 2];
                        gdst[g * 2 + 1] = lsrc[g * 2 + 1];
                    }
                }
                int rem = n & 7;
                for (int j = 0; j < rem; ++j) stage[b * SCAP + j] = stage[b * SCAP + ng * 8 + j];
                lcnt[b] = rem;
            } else {
                lcnt[b] = n;   // clamp if overflowed
            }
        }
        __syncthreads();
    }
    // final flush: pad remainder to a full group with sentinels
    for (int b = tid; b < NB; b += ATHR) {
        int n = min(lcnt[b], SCAP);
        if (n) {
            int ng = (n + 7) >> 3;
            for (int j = n; j < ng * 8; ++j) stage[b * SCAP + j] = -1;
            int base = atomicAdd(&tail[b], ng * 8);
            int4* gdst = (int4*)(pairs + b * PCAP + base);
            int4* lsrc = (int4*)(stage + b * SCAP);
            for (int g = 0; g < ng; ++g) {
                if (base + g * 8 + 8 <= PCAP) {
                    gdst[g * 2]     = lsrc[g * 2];
                    gdst[g * 2 + 1] = lsrc[g * 2 + 1];
                }
            }
        }
    }
}

// ---------------- Phase B: pairs -> CSR rows + fused dinv + fp16 xs table ----------------
// slist rows padded to mult-of-4 with N_NODES (the zero row).
// xh[node] = 16 halves (32B): h0..h9 = x*dinv, h10..h15 = 0. Row N of xh/th zeroed.
__global__ __launch_bounds__(1024) void csr_kernel(
    const int* __restrict__ tail, const int* __restrict__ pairs,
    const float* __restrict__ x, int* __restrict__ cnt, int* __restrict__ slist,
    float* __restrict__ dinv, u32* __restrict__ xh, u32* __restrict__ th, int N) {
    __shared__ int ofs[NPB];
    const int b = blockIdx.x, tid = threadIdx.x;
    if (tid < NPB) ofs[tid] = 0;
    __syncthreads();
    const int n = min(tail[b], PCAP);
    const int* pb = pairs + b * PCAP;
    const int node0 = b * NPB;
    for (int i = tid; i < n; i += 1024) {
        int p = pb[i];
        if (p >= 0) {
            int dl = p & 255;
            int pos = atomicAdd(&ofs[dl], 1);
            if (pos < CAP) slist[(size_t)(node0 + dl) * CAP + pos] = p >> 8;
        }
    }
    __syncthreads();
    if (tid < NPB) {
        int node = node0 + tid;
        if (node < N) {
            int deg = min(ofs[tid], CAP);
            cnt[node] = deg;
            int padded = (deg + 3) & ~3;
            for (int j = deg; j < padded; ++j) slist[(size_t)node * CAP + j] = N_NODES;
            float di = rsqrtf((float)deg + 1.0f);
            dinv[node] = di;
            u32 h[8];
#pragma unroll
            for (int k = 0; k < 5; ++k) {
                __half2 hh = __floats2half2_rn(x[(size_t)node * 10 + 2 * k] * di,
                                               x[(size_t)node * 10 + 2 * k + 1] * di);
                h[k] = *reinterpret_cast<u32*>(&hh);
            }
            h[5] = h[6] = h[7] = 0u;
            u32* row = xh + (size_t)node * 8;
            ((uint4*)row)[0] = make_uint4(h[0], h[1], h[2], h[3]);
            ((uint4*)row)[1] = make_uint4(h[4], h[5], h[6], h[7]);
        }
    }
    if (b == 0 && tid == 0) {   // zero row N of both gather tables
        u32* rx = xh + (size_t)N * 8;
        u32* rt = th + (size_t)N * 8;
        ((uint4*)rx)[0] = make_uint4(0, 0, 0, 0); ((uint4*)rx)[1] = make_uint4(0, 0, 0, 0);
        ((uint4*)rt)[0] = make_uint4(0, 0, 0, 0); ((uint4*)rt)[1] = make_uint4(0, 0, 0, 0);
    }
}

// ---------------- gather-aggregate from fp16 table: 2 threads/node, uint4 each ----------------
// cg0 accumulates halves 0..7, cg1 halves 8..15 (upper 6 are zeros). fp32 accumulation.
__global__ void aggh_kernel(const u32* __restrict__ vh, const int* __restrict__ cnt,
                            const int* __restrict__ slist, float* __restrict__ out12, int N) {
    int gt = blockIdx.x * blockDim.x + threadIdx.x;
    int i = gt >> 1, cg = gt & 1;
    if (i >= N) return;
    int degi = cnt[i];
    const int* lst = slist + (size_t)i * CAP;
    float a[8];
    {
        uint4 s = *(((const uint4*)(vh + (size_t)i * 8)) + cg);
        float2 f0 = h2f2(s.x), f1 = h2f2(s.y), f2 = h2f2(s.z), f3 = h2f2(s.w);
        a[0] = f0.x; a[1] = f0.y; a[2] = f1.x; a[3] = f1.y;
        a[4] = f2.x; a[5] = f2.y; a[6] = f3.x; a[7] = f3.y;
    }
    for (int k = 0; k < degi; k += 4) {
        int4 s4 = *reinterpret_cast<const int4*>(lst + k);
        uint4 q0 = *(((const uint4*)(vh + (size_t)s4.x * 8)) + cg);
        uint4 q1 = *(((const uint4*)(vh + (size_t)s4.y * 8)) + cg);
        uint4 q2 = *(((const uint4*)(vh + (size_t)s4.z * 8)) + cg);
        uint4 q3 = *(((const uint4*)(vh + (size_t)s4.w * 8)) + cg);
        float2 f;
        f = h2f2(q0.x); a[0] += f.x; a[1] += f.y;  f = h2f2(q0.y); a[2] += f.x; a[3] += f.y;
        f = h2f2(q0.z); a[4] += f.x; a[5] += f.y;  f = h2f2(q0.w); a[6] += f.x; a[7] += f.y;
        f = h2f2(q1.x); a[0] += f.x; a[1] += f.y;  f = h2f2(q1.y); a[2] += f.x; a[3] += f.y;
        f = h2f2(q1.z); a[4] += f.x; a[5] += f.y;  f = h2f2(q1.w); a[6] += f.x; a[7] += f.y;
        f = h2f2(q2.x); a[0] += f.x; a[1] += f.y;  f = h2f2(q2.y); a[2] += f.x; a[3] += f.y;
        f = h2f2(q2.z); a[4] += f.x; a[5] += f.y;  f = h2f2(q2.w); a[6] += f.x; a[7] += f.y;
        f = h2f2(q3.x); a[0] += f.x; a[1] += f.y;  f = h2f2(q3.y); a[2] += f.x; a[3] += f.y;
        f = h2f2(q3.z); a[4] += f.x; a[5] += f.y;  f = h2f2(q3.w); a[6] += f.x; a[7] += f.y;
    }
    float* orow = out12 + (size_t)i * 12;
    if (cg == 0) {
        ((float4*)orow)[0] = make_float4(a[0], a[1], a[2], a[3]);
        ((float4*)orow)[1] = make_float4(a[4], a[5], a[6], a[7]);
    } else {
        *(float2*)(orow + 8) = make_float2(a[0], a[1]);
    }
}

// ---------------- fused MLP: ax = dinv*agg ; y = relu(ax@W1+b1) ; th = half((y@W2)*dinv) ----------------
__global__ void layer12_kernel(const float* __restrict__ agg12, const float* __restrict__ dinv,
                               const float* __restrict__ W1, const float* __restrict__ b1,
                               const float* __restrict__ W2, u32* __restrict__ th, int N) {
    __shared__ float sW1[640];
    __shared__ float sW2[640];
    __shared__ float sb1[64];
    for (int k = threadIdx.x; k < 640; k += blockDim.x) { sW1[k] = W1[k]; sW2[k] = W2[k]; }
    if (threadIdx.x < 64) sb1[threadIdx.x] = b1[threadIdx.x];
    __syncthreads();
    int i = blockIdx.x * blockDim.x + threadIdx.x;
    if (i >= N) return;
    float di = dinv[i];
    float ax[10];
#pragma unroll
    for (int k = 0; k < 10; ++k) ax[k] = di * agg12[(size_t)i * 12 + k];
    float o[10];
#pragma unroll
    for (int k = 0; k < 10; ++k) o[k] = 0.f;
    for (int c = 0; c < 64; ++c) {
        float y = sb1[c];
#pragma unroll
        for (int k = 0; k < 10; ++k) y = fmaf(ax[k], sW1[k * 64 + c], y);
        y = fmaxf(y, 0.f);
#pragma unroll
        for (int k = 0; k < 10; ++k) o[k] = fmaf(y, sW2[c * 10 + k], o[k]);
    }
    u32 h[8];
#pragma unroll
    for (int k = 0; k < 5; ++k) {
        __half2 hh = __floats2half2_rn(o[2 * k] * di, o[2 * k + 1] * di);
        h[k] = *reinterpret_cast<u32*>(&hh);
    }
    h[5] = h[6] = h[7] = 0u;
    u32* row = th + (size_t)i * 8;
    ((uint4*)row)[0] = make_uint4(h[0], h[1], h[2], h[3]);
    ((uint4*)row)[1] = make_uint4(h[4], h[5], h[6], h[7]);
}

// ---------------- final: v = dinv*agg2 + b2 ; out = log_softmax(v) ----------------
__global__ void final_kernel(const float* __restrict__ agg2_12, const float* __restrict__ dinv,
                             const float* __restrict__ b2, float* __restrict__ out, int N) {
    int i = blockIdx.x * blockDim.x + threadIdx.x;
    if (i >= N) return;
    float di = dinv[i];
    float v[10];
    float m = -1e30f;
#pragma unroll
    for (int c = 0; c < 10; ++c) {
        float u = fmaf(di, agg2_12[(size_t)i * 12 + c], b2[c]);
        v[c] = u;
        m = fmaxf(m, u);
    }
    float s = 0.f;
#pragma unroll
    for (int c = 0; c < 10; ++c) s += __expf(v[c] - m);
    float lse = __logf(s) + m;
    float2* po = (float2*)(out + (size_t)i * 10);
#pragma unroll
    for (int c = 0; c < 5; ++c) po[c] = make_float2(v[2 * c] - lse, v[2 * c + 1] - lse);
}

extern "C" void kernel_launch(void* const* d_in, const int* in_sizes, int n_in,
                              void* d_out, int out_size, void* d_ws, size_t ws_size,
                              hipStream_t stream) {
    const float* x  = (const float*)d_in[0];
    const int*   ei = (const int*)d_in[1];
    const float* W1 = (const float*)d_in[2];
    const float* b1 = (const float*)d_in[3];
    const float* W2 = (const float*)d_in[4];
    const float* b2 = (const float*)d_in[5];
    float* out = (float*)d_out;

    const int N = N_NODES, E = N_EDGES;
    const int* src = ei;
    const int* dst = ei + E;

    // ws: [tail 512i][pairs NB*PCAP][cnt N][slist N*CAP][dinv N]
    //     [xh (N+1)*8 u32][th (N+1)*8 u32][agg12 N*12 f][agg2 N*12 f]
    int*   tail  = (int*)d_ws;
    int*   pairs = tail + 512;
    int*   cnt   = pairs + (size_t)NB * PCAP;
    int*   slist = cnt + N;
    float* dinv  = (float*)(slist + (size_t)N * CAP);
    u32*   xh    = (u32*)(dinv + N);
    u32*   th    = xh + (size_t)(N + 1) * 8;
    float* agg12 = (float*)(th + (size_t)(N + 1) * 8);
    float* agg2  = agg12 + (size_t)N * 12;

    zero_tail_kernel<<<1, 512, 0, stream>>>(tail);
    bucket_kernel<<<ABLK, ATHR, 0, stream>>>(src, dst, tail, pairs, E);
    csr_kernel<<<NB, 1024, 0, stream>>>(tail, pairs, x, cnt, slist, dinv, xh, th, N);
    aggh_kernel<<<(2 * N + 255) / 256, 256, 0, stream>>>(xh, cnt, slist, agg12, N);
    layer12_kernel<<<(N + 255) / 256, 256, 0, stream>>>(agg12, dinv, W1, b1, W2, th, N);
    aggh_kernel<<<(2 * N + 255) / 256, 256, 0, stream>>>(th, cnt, slist, agg2, N);
    final_kernel<<<(N + 255) / 256, 256, 0, stream>>>(agg2, dinv, b2, out, N);
}

// Round 12
// 93.266 us; speedup vs baseline: 1.2733x; 1.0544x over previous
//
#include <hip/hip_runtime.h>
#include <hip/hip_fp16.h>

#define N_NODES 100000
#define N_EDGES 1600000

#define NPB   256                      // nodes per bucket
#define NB    391                      // ceil(100000/256)
#define PCAP  8192                     // pairs capacity per bucket
#define ABLK  256                      // phase-A blocks
#define ATHR  1024                     // phase-A threads
#define CAP   64                       // per-node CSR row capacity

typedef unsigned int u32;

__device__ __forceinline__ float2 h2f2(u32 u) {
    __half2 h = *reinterpret_cast<__half2*>(&u);
    return __half22float2(h);
}

// zero the tail counters on the compute queue
__global__ void zero_tail_kernel(int* __restrict__ tail) {
    tail[threadIdx.x] = 0;
}

// ---------------- Phase A: two-pass bucketing with per-(block,bucket) reservation ----------------
// pair = (src<<8) | (dst & 255); bucket = dst >> 8; sentinel = -1
// Pass 1: count per-bucket edges of this block's chunk in LDS.
// Reserve: ONE tail atomic per (block,bucket), 8-aligned region; sentinels pad [n, ng8).
// Pass 2: scatter pairs into the block-private region (block-owned cachelines, no write-amp).
__global__ __launch_bounds__(ATHR) void bucket_kernel(
    const int* __restrict__ src, const int* __restrict__ dst,
    int* __restrict__ tail, int* __restrict__ pairs, int E) {
    __shared__ int lcnt[NB];
    __shared__ int bbase[NB];
    const int tid = threadIdx.x;
    for (int b = tid; b < NB; b += ATHR) lcnt[b] = 0;
    __syncthreads();

    const int chunk = (E + gridDim.x - 1) / gridDim.x;
    const int e0 = blockIdx.x * chunk;
    const int e1 = min(e0 + chunk, E);

    // pass 1: count
    for (int e = e0 + tid; e < e1; e += ATHR)
        atomicAdd(&lcnt[dst[e] >> 8], 1);
    __syncthreads();

    // reserve + write sentinels for the padding slots
    for (int b = tid; b < NB; b += ATHR) {
        int n = lcnt[b];
        int ng8 = (n + 7) & ~7;
        int base = 0;
        if (ng8) {
            base = atomicAdd(&tail[b], ng8);
            if (base + ng8 <= PCAP) {
                for (int j = n; j < ng8; ++j) pairs[b * PCAP + base + j] = -1;
            }
        }
        bbase[b] = base;
        lcnt[b] = 0;          // reuse as phase-2 cursor
    }
    __syncthreads();

    // pass 2: scatter pairs
    for (int e = e0 + tid; e < e1; e += ATHR) {
        int d = dst[e];
        int b = d >> 8;
        int p = (src[e] << 8) | (d & 255);
        int pos = atomicAdd(&lcnt[b], 1);
        int idx = bbase[b] + pos;
        if (idx < PCAP) pairs[b * PCAP + idx] = p;
    }
}

// ---------------- Phase B: pairs -> CSR rows + fused dinv + fp16 xs table ----------------
// slist rows padded to mult-of-4 with N_NODES (the zero row).
// xh[node] = 16 halves (32B): h0..h9 = x*dinv, h10..h15 = 0. Row N of xh/th zeroed.
__global__ __launch_bounds__(1024) void csr_kernel(
    const int* __restrict__ tail, const int* __restrict__ pairs,
    const float* __restrict__ x, int* __restrict__ cnt, int* __restrict__ slist,
    float* __restrict__ dinv, u32* __restrict__ xh, u32* __restrict__ th, int N) {
    __shared__ int ofs[NPB];
    const int b = blockIdx.x, tid = threadIdx.x;
    if (tid < NPB) ofs[tid] = 0;
    __syncthreads();
    const int n = min(tail[b], PCAP);
    const int* pb = pairs + b * PCAP;
    const int node0 = b * NPB;
    for (int i = tid; i < n; i += 1024) {
        int p = pb[i];
        if (p >= 0) {
            int dl = p & 255;
            int pos = atomicAdd(&ofs[dl], 1);
            if (pos < CAP) slist[(size_t)(node0 + dl) * CAP + pos] = p >> 8;
        }
    }
    __syncthreads();
    if (tid < NPB) {
        int node = node0 + tid;
        if (node < N) {
            int deg = min(ofs[tid], CAP);
            cnt[node] = deg;
            int padded = (deg + 3) & ~3;
            for (int j = deg; j < padded; ++j) slist[(size_t)node * CAP + j] = N_NODES;
            float di = rsqrtf((float)deg + 1.0f);
            dinv[node] = di;
            u32 h[8];
#pragma unroll
            for (int k = 0; k < 5; ++k) {
                __half2 hh = __floats2half2_rn(x[(size_t)node * 10 + 2 * k] * di,
                                               x[(size_t)node * 10 + 2 * k + 1] * di);
                h[k] = *reinterpret_cast<u32*>(&hh);
            }
            h[5] = h[6] = h[7] = 0u;
            u32* row = xh + (size_t)node * 8;
            ((uint4*)row)[0] = make_uint4(h[0], h[1], h[2], h[3]);
            ((uint4*)row)[1] = make_uint4(h[4], h[5], h[6], h[7]);
        }
    }
    if (b == 0 && tid == 0) {   // zero row N of both gather tables
        u32* rx = xh + (size_t)N * 8;
        u32* rt = th + (size_t)N * 8;
        ((uint4*)rx)[0] = make_uint4(0, 0, 0, 0); ((uint4*)rx)[1] = make_uint4(0, 0, 0, 0);
        ((uint4*)rt)[0] = make_uint4(0, 0, 0, 0); ((uint4*)rt)[1] = make_uint4(0, 0, 0, 0);
    }
}

// ---------------- gather-aggregate from fp16 table: 2 threads/node, uint4 each ----------------
// cg0 accumulates halves 0..7, cg1 halves 8..15 (upper 6 zeros). fp32 accumulation.
__global__ void aggh_kernel(const u32* __restrict__ vh, const int* __restrict__ cnt,
                            const int* __restrict__ slist, float* __restrict__ out12, int N) {
    int gt = blockIdx.x * blockDim.x + threadIdx.x;
    int i = gt >> 1, cg = gt & 1;
    if (i >= N) return;
    int degi = cnt[i];
    const int* lst = slist + (size_t)i * CAP;
    float a[8];
    {
        uint4 s = *(((const uint4*)(vh + (size_t)i * 8)) + cg);
        float2 f0 = h2f2(s.x), f1 = h2f2(s.y), f2 = h2f2(s.z), f3 = h2f2(s.w);
        a[0] = f0.x; a[1] = f0.y; a[2] = f1.x; a[3] = f1.y;
        a[4] = f2.x; a[5] = f2.y; a[6] = f3.x; a[7] = f3.y;
    }
    for (int k = 0; k < degi; k += 4) {
        int4 s4 = *reinterpret_cast<const int4*>(lst + k);
        uint4 q0 = *(((const uint4*)(vh + (size_t)s4.x * 8)) + cg);
        uint4 q1 = *(((const uint4*)(vh + (size_t)s4.y * 8)) + cg);
        uint4 q2 = *(((const uint4*)(vh + (size_t)s4.z * 8)) + cg);
        uint4 q3 = *(((const uint4*)(vh + (size_t)s4.w * 8)) + cg);
        float2 f;
        f = h2f2(q0.x); a[0] += f.x; a[1] += f.y;  f = h2f2(q0.y); a[2] += f.x; a[3] += f.y;
        f = h2f2(q0.z); a[4] += f.x; a[5] += f.y;  f = h2f2(q0.w); a[6] += f.x; a[7] += f.y;
        f = h2f2(q1.x); a[0] += f.x; a[1] += f.y;  f = h2f2(q1.y); a[2] += f.x; a[3] += f.y;
        f = h2f2(q1.z); a[4] += f.x; a[5] += f.y;  f = h2f2(q1.w); a[6] += f.x; a[7] += f.y;
        f = h2f2(q2.x); a[0] += f.x; a[1] += f.y;  f = h2f2(q2.y); a[2] += f.x; a[3] += f.y;
        f = h2f2(q2.z); a[4] += f.x; a[5] += f.y;  f = h2f2(q2.w); a[6] += f.x; a[7] += f.y;
        f = h2f2(q3.x); a[0] += f.x; a[1] += f.y;  f = h2f2(q3.y); a[2] += f.x; a[3] += f.y;
        f = h2f2(q3.z); a[4] += f.x; a[5] += f.y;  f = h2f2(q3.w); a[6] += f.x; a[7] += f.y;
    }
    float* orow = out12 + (size_t)i * 12;
    if (cg == 0) {
        ((float4*)orow)[0] = make_float4(a[0], a[1], a[2], a[3]);
        ((float4*)orow)[1] = make_float4(a[4], a[5], a[6], a[7]);
    } else {
        *(float2*)(orow + 8) = make_float2(a[0], a[1]);
    }
}

// ---------------- fused MLP: ax = dinv*agg ; y = relu(ax@W1+b1) ; th = half((y@W2)*dinv) ----------------
__global__ void layer12_kernel(const float* __restrict__ agg12, const float* __restrict__ dinv,
                               const float* __restrict__ W1, const float* __restrict__ b1,
                               const float* __restrict__ W2, u32* __restrict__ th, int N) {
    __shared__ float sW1[640];
    __shared__ float sW2[640];
    __shared__ float sb1[64];
    for (int k = threadIdx.x; k < 640; k += blockDim.x) { sW1[k] = W1[k]; sW2[k] = W2[k]; }
    if (threadIdx.x < 64) sb1[threadIdx.x] = b1[threadIdx.x];
    __syncthreads();
    int i = blockIdx.x * blockDim.x + threadIdx.x;
    if (i >= N) return;
    float di = dinv[i];
    float ax[10];
#pragma unroll
    for (int k = 0; k < 10; ++k) ax[k] = di * agg12[(size_t)i * 12 + k];
    float o[10];
#pragma unroll
    for (int k = 0; k < 10; ++k) o[k] = 0.f;
    for (int c = 0; c < 64; ++c) {
        float y = sb1[c];
#pragma unroll
        for (int k = 0; k < 10; ++k) y = fmaf(ax[k], sW1[k * 64 + c], y);
        y = fmaxf(y, 0.f);
#pragma unroll
        for (int k = 0; k < 10; ++k) o[k] = fmaf(y, sW2[c * 10 + k], o[k]);
    }
    u32 h[8];
#pragma unroll
    for (int k = 0; k < 5; ++k) {
        __half2 hh = __floats2half2_rn(o[2 * k] * di, o[2 * k + 1] * di);
        h[k] = *reinterpret_cast<u32*>(&hh);
    }
    h[5] = h[6] = h[7] = 0u;
    u32* row = th + (size_t)i * 8;
    ((uint4*)row)[0] = make_uint4(h[0], h[1], h[2], h[3]);
    ((uint4*)row)[1] = make_uint4(h[4], h[5], h[6], h[7]);
}

// ---------------- fused agg2 + log-softmax: 2 threads/node, shfl handoff ----------------
// cg0 gathers sums 0..7, cg1 gathers 8..9; cg1 -> cg0 via 2x shfl_xor; cg0 writes output.
__global__ void aggout_kernel(const u32* __restrict__ vh, const int* __restrict__ cnt,
                              const int* __restrict__ slist, const float* __restrict__ dinv,
                              const float* __restrict__ b2, float* __restrict__ out, int N) {
    int gt = blockIdx.x * blockDim.x + threadIdx.x;
    int i = gt >> 1, cg = gt & 1;
    bool valid = (i < N);
    float a[8];
#pragma unroll
    for (int k = 0; k < 8; ++k) a[k] = 0.f;
    if (valid) {
        int degi = cnt[i];
        const int* lst = slist + (size_t)i * CAP;
        {
            uint4 s = *(((const uint4*)(vh + (size_t)i * 8)) + cg);
            float2 f0 = h2f2(s.x), f1 = h2f2(s.y), f2 = h2f2(s.z), f3 = h2f2(s.w);
            a[0] = f0.x; a[1] = f0.y; a[2] = f1.x; a[3] = f1.y;
            a[4] = f2.x; a[5] = f2.y; a[6] = f3.x; a[7] = f3.y;
        }
        for (int k = 0; k < degi; k += 4) {
            int4 s4 = *reinterpret_cast<const int4*>(lst + k);
            uint4 q0 = *(((const uint4*)(vh + (size_t)s4.x * 8)) + cg);
            uint4 q1 = *(((const uint4*)(vh + (size_t)s4.y * 8)) + cg);
            uint4 q2 = *(((const uint4*)(vh + (size_t)s4.z * 8)) + cg);
            uint4 q3 = *(((const uint4*)(vh + (size_t)s4.w * 8)) + cg);
            float2 f;
            f = h2f2(q0.x); a[0] += f.x; a[1] += f.y;  f = h2f2(q0.y); a[2] += f.x; a[3] += f.y;
            f = h2f2(q0.z); a[4] += f.x; a[5] += f.y;  f = h2f2(q0.w); a[6] += f.x; a[7] += f.y;
            f = h2f2(q1.x); a[0] += f.x; a[1] += f.y;  f = h2f2(q1.y); a[2] += f.x; a[3] += f.y;
            f = h2f2(q1.z); a[4] += f.x; a[5] += f.y;  f = h2f2(q1.w); a[6] += f.x; a[7] += f.y;
            f = h2f2(q2.x); a[0] += f.x; a[1] += f.y;  f = h2f2(q2.y); a[2] += f.x; a[3] += f.y;
            f = h2f2(q2.z); a[4] += f.x; a[5] += f.y;  f = h2f2(q2.w); a[6] += f.x; a[7] += f.y;
            f = h2f2(q3.x); a[0] += f.x; a[1] += f.y;  f = h2f2(q3.y); a[2] += f.x; a[3] += f.y;
            f = h2f2(q3.z); a[4] += f.x; a[5] += f.y;  f = h2f2(q3.w); a[6] += f.x; a[7] += f.y;
        }
    }
    // cg1's partial sums for classes 8,9 live in its a[0],a[1]
    float v8 = __shfl_xor(a[0], 1);
    float v9 = __shfl_xor(a[1], 1);
    if (valid && cg == 0) {
        float di = dinv[i];
        float v[10] = { a[0], a[1], a[2], a[3], a[4], a[5], a[6], a[7], v8, v9 };
        float m = -1e30f;
#pragma unroll
        for (int c = 0; c < 10; ++c) {
            v[c] = fmaf(di, v[c], b2[c]);
            m = fmaxf(m, v[c]);
        }
        float s = 0.f;
#pragma unroll
        for (int c = 0; c < 10; ++c) s += __expf(v[c] - m);
        float lse = __logf(s) + m;
        float2* po = (float2*)(out + (size_t)i * 10);
#pragma unroll
        for (int c = 0; c < 5; ++c) po[c] = make_float2(v[2 * c] - lse, v[2 * c + 1] - lse);
    }
}

extern "C" void kernel_launch(void* const* d_in, const int* in_sizes, int n_in,
                              void* d_out, int out_size, void* d_ws, size_t ws_size,
                              hipStream_t stream) {
    const float* x  = (const float*)d_in[0];
    const int*   ei = (const int*)d_in[1];
    const float* W1 = (const float*)d_in[2];
    const float* b1 = (const float*)d_in[3];
    const float* W2 = (const float*)d_in[4];
    const float* b2 = (const float*)d_in[5];
    float* out = (float*)d_out;

    const int N = N_NODES, E = N_EDGES;
    const int* src = ei;
    const int* dst = ei + E;

    // ws: [tail 512i][pairs NB*PCAP][cnt N][slist N*CAP][dinv N]
    //     [xh (N+1)*8 u32][th (N+1)*8 u32][agg12 N*12 f]
    int*   tail  = (int*)d_ws;
    int*   pairs = tail + 512;
    int*   cnt   = pairs + (size_t)NB * PCAP;
    int*   slist = cnt + N;
    float* dinv  = (float*)(slist + (size_t)N * CAP);
    u32*   xh    = (u32*)(dinv + N);
    u32*   th    = xh + (size_t)(N + 1) * 8;
    float* agg12 = (float*)(th + (size_t)(N + 1) * 8);

    zero_tail_kernel<<<1, 512, 0, stream>>>(tail);
    bucket_kernel<<<ABLK, ATHR, 0, stream>>>(src, dst, tail, pairs, E);
    csr_kernel<<<NB, 1024, 0, stream>>>(tail, pairs, x, cnt, slist, dinv, xh, th, N);
    aggh_kernel<<<(2 * N + 255) / 256, 256, 0, stream>>>(xh, cnt, slist, agg12, N);
    layer12_kernel<<<(N + 255) / 256, 256, 0, stream>>>(agg12, dinv, W1, b1, W2, th, N);
    aggout_kernel<<<(2 * N + 255) / 256, 256, 0, stream>>>(th, cnt, slist, dinv, b2, out, N);
}

// Round 13
// 83.174 us; speedup vs baseline: 1.4278x; 1.1213x over previous
//
#include <hip/hip_runtime.h>
#include <hip/hip_fp16.h>

#define N_NODES 100000
#define N_EDGES 1600000

#define NPB   256                      // nodes per bucket
#define NB    391                      // ceil(100000/256)
#define ABLK  256                      // bucketing blocks
#define ATHR  1024                     // bucketing threads
#define BSLOT 64                       // slots per (block,bucket) cell; Poisson(16), P(>=64)~0
#define CAP   64                       // per-node CSR row capacity

typedef unsigned int u32;

__device__ __forceinline__ float2 h2f2(u32 u) {
    __half2 h = *reinterpret_cast<__half2*>(&u);
    return __half22float2(h);
}

// ---------------- Phase A: SINGLE-PASS bucketing into static (block,bucket) cells ----------------
// pair = (src<<8) | (dst & 255); cell = pairs[b*ABLK*BSLOT + blk*BSLOT + pos]
// No global atomics, no tail array, no sentinels. gcnt[b*ABLK+blk] = count.
__global__ __launch_bounds__(ATHR) void bucket_kernel(
    const int* __restrict__ src, const int* __restrict__ dst,
    int* __restrict__ gcnt, int* __restrict__ pairs, int E) {
    __shared__ int lcnt[NB];
    const int tid = threadIdx.x, blk = blockIdx.x;
    for (int b = tid; b < NB; b += ATHR) lcnt[b] = 0;
    __syncthreads();

    const int chunk = (E + gridDim.x - 1) / gridDim.x;
    const int e0 = blk * chunk;
    const int e1 = min(e0 + chunk, E);

    for (int e = e0 + tid; e < e1; e += ATHR) {
        int d = dst[e];
        int b = d >> 8;
        int p = (src[e] << 8) | (d & 255);
        int pos = atomicAdd(&lcnt[b], 1);
        if (pos < BSLOT) pairs[(size_t)b * (ABLK * BSLOT) + blk * BSLOT + pos] = p;
    }
    __syncthreads();
    for (int b = tid; b < NB; b += ATHR)
        gcnt[b * ABLK + blk] = min(lcnt[b], BSLOT);
}

// ---------------- Phase B: cells -> CSR rows + fused dinv + fp16 xs table ----------------
// slist rows padded to mult-of-4 with N_NODES (the zero row).
// xh[node] = 16 halves (32B): h0..h9 = x*dinv, rest 0. Row N of xh/th zeroed.
__global__ __launch_bounds__(1024) void csr_kernel(
    const int* __restrict__ gcnt, const int* __restrict__ pairs,
    const float* __restrict__ x, int* __restrict__ cnt, int* __restrict__ slist,
    float* __restrict__ dinv, u32* __restrict__ xh, u32* __restrict__ th, int N) {
    __shared__ int ofs[NPB];
    __shared__ int gc[ABLK];
    const int b = blockIdx.x, tid = threadIdx.x;
    if (tid < NPB) ofs[tid] = 0;
    if (tid < ABLK) gc[tid] = gcnt[b * ABLK + tid];
    __syncthreads();
    const int* pb = pairs + (size_t)b * (ABLK * BSLOT);
    const int node0 = b * NPB;
    // coalesced predicated scan: threads 0..63 cover cell r's 64 slots, etc.
    for (int i = tid; i < ABLK * BSLOT; i += 1024) {
        int r = i >> 6;          // BSLOT = 64
        int j = i & 63;
        if (j < gc[r]) {
            int p = pb[i];
            int dl = p & 255;
            int pos = atomicAdd(&ofs[dl], 1);
            if (pos < CAP) slist[(size_t)(node0 + dl) * CAP + pos] = p >> 8;
        }
    }
    __syncthreads();
    if (tid < NPB) {
        int node = node0 + tid;
        if (node < N) {
            int deg = min(ofs[tid], CAP);
            cnt[node] = deg;
            int padded = (deg + 3) & ~3;
            for (int j = deg; j < padded; ++j) slist[(size_t)node * CAP + j] = N_NODES;
            float di = rsqrtf((float)deg + 1.0f);
            dinv[node] = di;
            u32 h[8];
#pragma unroll
            for (int k = 0; k < 5; ++k) {
                __half2 hh = __floats2half2_rn(x[(size_t)node * 10 + 2 * k] * di,
                                               x[(size_t)node * 10 + 2 * k + 1] * di);
                h[k] = *reinterpret_cast<u32*>(&hh);
            }
            h[5] = h[6] = h[7] = 0u;
            u32* row = xh + (size_t)node * 8;
            ((uint4*)row)[0] = make_uint4(h[0], h[1], h[2], h[3]);
            ((uint4*)row)[1] = make_uint4(h[4], h[5], h[6], h[7]);
        }
    }
    if (b == 0 && tid == 0) {   // zero row N of both gather tables
        u32* rx = xh + (size_t)N * 8;
        u32* rt = th + (size_t)N * 8;
        ((uint4*)rx)[0] = make_uint4(0, 0, 0, 0); ((uint4*)rx)[1] = make_uint4(0, 0, 0, 0);
        ((uint4*)rt)[0] = make_uint4(0, 0, 0, 0); ((uint4*)rt)[1] = make_uint4(0, 0, 0, 0);
    }
}

// ---------------- fused gather + MLP: 2 threads/node, shfl exchange, split c-loop ----------------
// gather (as aggh) -> 8 shfl_xor gives both lanes the 10 aggregate sums ->
// ax = dinv*agg -> each lane runs 32 of the 64 hidden units -> 10 shfl-reduce ->
// both lanes hold o[10] -> lane cg writes uint4 #cg of th row (fp16, *dinv).
__global__ void aggmlp_kernel(const u32* __restrict__ vh, const int* __restrict__ cnt,
                              const int* __restrict__ slist, const float* __restrict__ dinv,
                              const float* __restrict__ W1, const float* __restrict__ b1,
                              const float* __restrict__ W2, u32* __restrict__ th, int N) {
    __shared__ float sW1[640];
    __shared__ float sW2[640];
    __shared__ float sb1[64];
    for (int k = threadIdx.x; k < 640; k += blockDim.x) { sW1[k] = W1[k]; sW2[k] = W2[k]; }
    if (threadIdx.x < 64) sb1[threadIdx.x] = b1[threadIdx.x];
    __syncthreads();
    int gt = blockIdx.x * blockDim.x + threadIdx.x;
    int i = gt >> 1, cg = gt & 1;
    if (i >= N) return;
    int degi = cnt[i];
    const int* lst = slist + (size_t)i * CAP;
    float a[8];
    {
        uint4 s = *(((const uint4*)(vh + (size_t)i * 8)) + cg);
        float2 f0 = h2f2(s.x), f1 = h2f2(s.y), f2 = h2f2(s.z), f3 = h2f2(s.w);
        a[0] = f0.x; a[1] = f0.y; a[2] = f1.x; a[3] = f1.y;
        a[4] = f2.x; a[5] = f2.y; a[6] = f3.x; a[7] = f3.y;
    }
    for (int k = 0; k < degi; k += 4) {
        int4 s4 = *reinterpret_cast<const int4*>(lst + k);
        uint4 q0 = *(((const uint4*)(vh + (size_t)s4.x * 8)) + cg);
        uint4 q1 = *(((const uint4*)(vh + (size_t)s4.y * 8)) + cg);
        uint4 q2 = *(((const uint4*)(vh + (size_t)s4.z * 8)) + cg);
        uint4 q3 = *(((const uint4*)(vh + (size_t)s4.w * 8)) + cg);
        float2 f;
        f = h2f2(q0.x); a[0] += f.x; a[1] += f.y;  f = h2f2(q0.y); a[2] += f.x; a[3] += f.y;
        f = h2f2(q0.z); a[4] += f.x; a[5] += f.y;  f = h2f2(q0.w); a[6] += f.x; a[7] += f.y;
        f = h2f2(q1.x); a[0] += f.x; a[1] += f.y;  f = h2f2(q1.y); a[2] += f.x; a[3] += f.y;
        f = h2f2(q1.z); a[4] += f.x; a[5] += f.y;  f = h2f2(q1.w); a[6] += f.x; a[7] += f.y;
        f = h2f2(q2.x); a[0] += f.x; a[1] += f.y;  f = h2f2(q2.y); a[2] += f.x; a[3] += f.y;
        f = h2f2(q2.z); a[4] += f.x; a[5] += f.y;  f = h2f2(q2.w); a[6] += f.x; a[7] += f.y;
        f = h2f2(q3.x); a[0] += f.x; a[1] += f.y;  f = h2f2(q3.y); a[2] += f.x; a[3] += f.y;
        f = h2f2(q3.z); a[4] += f.x; a[5] += f.y;  f = h2f2(q3.w); a[6] += f.x; a[7] += f.y;
    }
    // exchange: cg0 has class-sums 0..7 in a[0..7]; cg1 has 8,9 in a[0..1]
    float t0 = __shfl_xor(a[0], 1), t1 = __shfl_xor(a[1], 1);
    float t2 = __shfl_xor(a[2], 1), t3 = __shfl_xor(a[3], 1);
    float t4 = __shfl_xor(a[4], 1), t5 = __shfl_xor(a[5], 1);
    float t6 = __shfl_xor(a[6], 1), t7 = __shfl_xor(a[7], 1);
    float di = dinv[i];
    float ax[10];
    if (cg == 0) {
        ax[0]=a[0]; ax[1]=a[1]; ax[2]=a[2]; ax[3]=a[3]; ax[4]=a[4];
        ax[5]=a[5]; ax[6]=a[6]; ax[7]=a[7]; ax[8]=t0;   ax[9]=t1;
    } else {
        ax[0]=t0; ax[1]=t1; ax[2]=t2; ax[3]=t3; ax[4]=t4;
        ax[5]=t5; ax[6]=t6; ax[7]=t7; ax[8]=a[0]; ax[9]=a[1];
    }
#pragma unroll
    for (int k = 0; k < 10; ++k) ax[k] *= di;
    float o[10];
#pragma unroll
    for (int k = 0; k < 10; ++k) o[k] = 0.f;
    const int c0 = cg * 32;
    for (int c = c0; c < c0 + 32; ++c) {
        float y = sb1[c];
#pragma unroll
        for (int k = 0; k < 10; ++k) y = fmaf(ax[k], sW1[k * 64 + c], y);
        y = fmaxf(y, 0.f);
#pragma unroll
        for (int k = 0; k < 10; ++k) o[k] = fmaf(y, sW2[c * 10 + k], o[k]);
    }
#pragma unroll
    for (int k = 0; k < 10; ++k) o[k] += __shfl_xor(o[k], 1);   // both lanes: full sums
#pragma unroll
    for (int k = 0; k < 10; ++k) o[k] *= di;
    u32* row = th + (size_t)i * 8;
    if (cg == 0) {
        __half2 h0 = __floats2half2_rn(o[0], o[1]);
        __half2 h1 = __floats2half2_rn(o[2], o[3]);
        __half2 h2 = __floats2half2_rn(o[4], o[5]);
        __half2 h3 = __floats2half2_rn(o[6], o[7]);
        ((uint4*)row)[0] = make_uint4(*reinterpret_cast<u32*>(&h0), *reinterpret_cast<u32*>(&h1),
                                      *reinterpret_cast<u32*>(&h2), *reinterpret_cast<u32*>(&h3));
    } else {
        __half2 h4 = __floats2half2_rn(o[8], o[9]);
        ((uint4*)row)[1] = make_uint4(*reinterpret_cast<u32*>(&h4), 0u, 0u, 0u);
    }
}

// ---------------- fused agg2 + log-softmax: 2 threads/node, shfl handoff ----------------
__global__ void aggout_kernel(const u32* __restrict__ vh, const int* __restrict__ cnt,
                              const int* __restrict__ slist, const float* __restrict__ dinv,
                              const float* __restrict__ b2, float* __restrict__ out, int N) {
    int gt = blockIdx.x * blockDim.x + threadIdx.x;
    int i = gt >> 1, cg = gt & 1;
    bool valid = (i < N);
    float a[8];
#pragma unroll
    for (int k = 0; k < 8; ++k) a[k] = 0.f;
    if (valid) {
        int degi = cnt[i];
        const int* lst = slist + (size_t)i * CAP;
        {
            uint4 s = *(((const uint4*)(vh + (size_t)i * 8)) + cg);
            float2 f0 = h2f2(s.x), f1 = h2f2(s.y), f2 = h2f2(s.z), f3 = h2f2(s.w);
            a[0] = f0.x; a[1] = f0.y; a[2] = f1.x; a[3] = f1.y;
            a[4] = f2.x; a[5] = f2.y; a[6] = f3.x; a[7] = f3.y;
        }
        for (int k = 0; k < degi; k += 4) {
            int4 s4 = *reinterpret_cast<const int4*>(lst + k);
            uint4 q0 = *(((const uint4*)(vh + (size_t)s4.x * 8)) + cg);
            uint4 q1 = *(((const uint4*)(vh + (size_t)s4.y * 8)) + cg);
            uint4 q2 = *(((const uint4*)(vh + (size_t)s4.z * 8)) + cg);
            uint4 q3 = *(((const uint4*)(vh + (size_t)s4.w * 8)) + cg);
            float2 f;
            f = h2f2(q0.x); a[0] += f.x; a[1] += f.y;  f = h2f2(q0.y); a[2] += f.x; a[3] += f.y;
            f = h2f2(q0.z); a[4] += f.x; a[5] += f.y;  f = h2f2(q0.w); a[6] += f.x; a[7] += f.y;
            f = h2f2(q1.x); a[0] += f.x; a[1] += f.y;  f = h2f2(q1.y); a[2] += f.x; a[3] += f.y;
            f = h2f2(q1.z); a[4] += f.x; a[5] += f.y;  f = h2f2(q1.w); a[6] += f.x; a[7] += f.y;
            f = h2f2(q2.x); a[0] += f.x; a[1] += f.y;  f = h2f2(q2.y); a[2] += f.x; a[3] += f.y;
            f = h2f2(q2.z); a[4] += f.x; a[5] += f.y;  f = h2f2(q2.w); a[6] += f.x; a[7] += f.y;
            f = h2f2(q3.x); a[0] += f.x; a[1] += f.y;  f = h2f2(q3.y); a[2] += f.x; a[3] += f.y;
            f = h2f2(q3.z); a[4] += f.x; a[5] += f.y;  f = h2f2(q3.w); a[6] += f.x; a[7] += f.y;
        }
    }
    float v8 = __shfl_xor(a[0], 1);
    float v9 = __shfl_xor(a[1], 1);
    if (valid && cg == 0) {
        float di = dinv[i];
        float v[10] = { a[0], a[1], a[2], a[3], a[4], a[5], a[6], a[7], v8, v9 };
        float m = -1e30f;
#pragma unroll
        for (int c = 0; c < 10; ++c) {
            v[c] = fmaf(di, v[c], b2[c]);
            m = fmaxf(m, v[c]);
        }
        float s = 0.f;
#pragma unroll
        for (int c = 0; c < 10; ++c) s += __expf(v[c] - m);
        float lse = __logf(s) + m;
        float2* po = (float2*)(out + (size_t)i * 10);
#pragma unroll
        for (int c = 0; c < 5; ++c) po[c] = make_float2(v[2 * c] - lse, v[2 * c + 1] - lse);
    }
}

extern "C" void kernel_launch(void* const* d_in, const int* in_sizes, int n_in,
                              void* d_out, int out_size, void* d_ws, size_t ws_size,
                              hipStream_t stream) {
    const float* x  = (const float*)d_in[0];
    const int*   ei = (const int*)d_in[1];
    const float* W1 = (const float*)d_in[2];
    const float* b1 = (const float*)d_in[3];
    const float* W2 = (const float*)d_in[4];
    const float* b2 = (const float*)d_in[5];
    float* out = (float*)d_out;

    const int N = N_NODES, E = N_EDGES;
    const int* src = ei;
    const int* dst = ei + E;

    // ws: [gcnt NB*ABLK][pairs NB*ABLK*BSLOT][cnt N][slist N*CAP][dinv N]
    //     [xh (N+1)*8 u32][th (N+1)*8 u32]
    int*   gcnt  = (int*)d_ws;
    int*   pairs = gcnt + (size_t)NB * ABLK;
    int*   cnt   = pairs + (size_t)NB * ABLK * BSLOT;
    int*   slist = cnt + N;
    float* dinv  = (float*)(slist + (size_t)N * CAP);
    u32*   xh    = (u32*)(dinv + N);
    u32*   th    = xh + (size_t)(N + 1) * 8;

    bucket_kernel<<<ABLK, ATHR, 0, stream>>>(src, dst, gcnt, pairs, E);
    csr_kernel<<<NB, 1024, 0, stream>>>(gcnt, pairs, x, cnt, slist, dinv, xh, th, N);
    aggmlp_kernel<<<(2 * N + 255) / 256, 256, 0, stream>>>(xh, cnt, slist, dinv, W1, b1, W2, th, N);
    aggout_kernel<<<(2 * N + 255) / 256, 256, 0, stream>>>(th, cnt, slist, dinv, b2, out, N);
}